// Round 6
// baseline (493.601 us; speedup 1.0000x reference)
//
#include <hip/hip_runtime.h>
#include <math.h>

// Problem constants (fixed by setup_inputs)
#define B_   64
#define N_   16384
#define C_   64
#define S_   16                    // N-splits for partial stats
#define ROWS_PER_BLK (N_ / S_)     // 1024 rows of C_ floats per stats block
#define EPS_ 1e-6f
#define ALPHA_MAX_ 0.5f

// ---------------------------------------------------------------------------
// Kernel 1: per-(b, channel) partial sum / sumsq over an N-slice.
// Grid: B_*S_ blocks of 256 threads. Each wave reads a contiguous 1 KB
// (float4 per lane), so loads are perfectly coalesced. (Proven; at the
// read-only BW ceiling.)
// ---------------------------------------------------------------------------
__global__ __launch_bounds__(256) void stats_partial_kernel(
    const float* __restrict__ x,
    float* __restrict__ sumP,   // [B_*S_][C_]
    float* __restrict__ sqP)    // [B_*S_][C_]
{
    const int bid = blockIdx.x;        // = b*S_ + s
    const int b   = bid >> 4;          // /S_ (S_==16)
    const int s   = bid & 15;

    const float4* xp = (const float4*)(x + ((size_t)b * N_ + (size_t)s * ROWS_PER_BLK) * C_);

    const int tid  = threadIdx.x;
    const int cg   = tid & 15;         // channel-group: covers channels cg*4..cg*4+3
    const int row0 = tid >> 4;         // 0..15

    float4 sum = make_float4(0.f, 0.f, 0.f, 0.f);
    float4 sq  = make_float4(0.f, 0.f, 0.f, 0.f);

    // Each row has C_/4 = 16 float4s; thread walks rows with stride 16.
    #pragma unroll 8
    for (int r = row0; r < ROWS_PER_BLK; r += 16) {
        float4 v = xp[r * 16 + cg];
        sum.x += v.x; sum.y += v.y; sum.z += v.z; sum.w += v.w;
        sq.x = fmaf(v.x, v.x, sq.x); sq.y = fmaf(v.y, v.y, sq.y);
        sq.z = fmaf(v.z, v.z, sq.z); sq.w = fmaf(v.w, v.w, sq.w);
    }

    __shared__ float lds[256][8];
    lds[tid][0] = sum.x; lds[tid][1] = sum.y; lds[tid][2] = sum.z; lds[tid][3] = sum.w;
    lds[tid][4] = sq.x;  lds[tid][5] = sq.y;  lds[tid][6] = sq.z;  lds[tid][7] = sq.w;
    __syncthreads();

    // Reduce across the 16 row-threads sharing each channel-group.
    // tid layout = row0*16 + cg, so strides of 16 preserve cg.
    for (int off = 128; off >= 16; off >>= 1) {
        if (tid < off) {
            #pragma unroll
            for (int k = 0; k < 8; ++k) lds[tid][k] += lds[tid + off][k];
        }
        __syncthreads();
    }

    if (tid < 16) {
        float* sp = sumP + (size_t)bid * C_ + tid * 4;
        float* qp = sqP  + (size_t)bid * C_ + tid * 4;
        sp[0] = lds[tid][0]; sp[1] = lds[tid][1]; sp[2] = lds[tid][2]; sp[3] = lds[tid][3];
        qp[0] = lds[tid][4]; qp[1] = lds[tid][5]; qp[2] = lds[tid][6]; qp[3] = lds[tid][7];
    }
}

// ---------------------------------------------------------------------------
// Kernel 2 (fused finalize + apply): each block owns a contiguous 128 KB
// chunk of one sample (forward order — reversal was measured neutral).
// Threads 0..63 recompute that sample's scale/bias from the partials
// (16 KiB, L2-resident; hidden under the x prefetch issued first).
//
// Stores are PLAIN cached float4 stores this round: the nt-store variant
// was adopted for an L3-protection theory that is now disproven (the
// harness's 1 GiB workspace re-poison fills run between my two passes and
// sweep L3 regardless). Plain stores match the 6.29 TB/s copy-µbench and
// 6.5 TB/s fill write path; this is a single-variable A/B vs R4 (484.2 µs,
// nt stores) to test whether nt writes tax HBM write efficiency.
// ---------------------------------------------------------------------------
#define PRE 8                      // float4 prefetched per thread before scb
__global__ __launch_bounds__(256) void apply_fused_kernel(
    const float* __restrict__ x,
    const float* __restrict__ sumP,
    const float* __restrict__ sqP,
    const float* __restrict__ alpha_u,      // [B_]
    const float* __restrict__ select_noise, // [B_][B_]
    const int*   __restrict__ dom,          // [B_]
    const int*   __restrict__ cls,          // [B_]
    float* __restrict__ out)
{
    const int tid = threadIdx.x;
    const int b   = blockIdx.x >> 5;          // 32 blocks per sample

    const size_t base = (size_t)blockIdx.x * 8192 + tid;  // float4 index
    const float4* __restrict__ xin = (const float4*)x;
    float4* __restrict__ op = (float4*)out;

    // ---- issue prefetch of the first PRE float4s (saturate HBM from t0) ----
    float4 pre[PRE];
    #pragma unroll
    for (int it = 0; it < PRE; ++it) pre[it] = xin[base + (size_t)it * 256];

    // ---- per-block scale/bias (threads 0..63, c = tid) ----
    __shared__ float scb[2][C_];
    if (tid < C_) {
        const int myCls = cls[b];
        const int myDom = dom[b];
        float best = -1.0f;   // noise is uniform[0,1), any valid score beats -1
        int   bi   = -1;
        for (int j = 0; j < B_; ++j) {
            if (cls[j] == myCls && dom[j] != myDom) {
                float sc = select_noise[b * B_ + j];
                if (sc > best) { best = sc; bi = j; }
            }
        }
        const int idx = (bi < 0) ? b : bi;

        double s1 = 0.0, q1 = 0.0, s2 = 0.0, q2 = 0.0;
        for (int s = 0; s < S_; ++s) {
            s1 += (double)sumP[((size_t)b   * S_ + s) * C_ + tid];
            q1 += (double)sqP [((size_t)b   * S_ + s) * C_ + tid];
            s2 += (double)sumP[((size_t)idx * S_ + s) * C_ + tid];
            q2 += (double)sqP [((size_t)idx * S_ + s) * C_ + tid];
        }
        const double n = (double)N_;
        const float mu   = (float)(s1 / n);
        const float sig  = sqrtf((float)((q1 - s1 * s1 / n) / (n - 1.0)) + EPS_);
        const float mu2  = (float)(s2 / n);
        const float sig2 = sqrtf((float)((q2 - s2 * s2 / n) / (n - 1.0)) + EPS_);

        const float a = alpha_u[b] * ALPHA_MAX_;
        const float mu_mix  = mu  * a + mu2  * (1.0f - a);
        const float sig_mix = sig * a + sig2 * (1.0f - a);

        const float scale = sig_mix / sig;
        scb[0][tid] = scale;
        scb[1][tid] = mu_mix - mu * scale;
    }
    __syncthreads();

    const int c0 = (tid & 15) * 4;
    const float4 sc = make_float4(scb[0][c0], scb[0][c0+1], scb[0][c0+2], scb[0][c0+3]);
    const float4 bs = make_float4(scb[1][c0], scb[1][c0+1], scb[1][c0+2], scb[1][c0+3]);

    // ---- drain prefetched portion ----
    #pragma unroll
    for (int it = 0; it < PRE; ++it) {
        float4 o;
        o.x = fmaf(pre[it].x, sc.x, bs.x);
        o.y = fmaf(pre[it].y, sc.y, bs.y);
        o.z = fmaf(pre[it].z, sc.z, bs.z);
        o.w = fmaf(pre[it].w, sc.w, bs.w);
        op[base + (size_t)it * 256] = o;
    }
    // ---- stream the rest (24 iterations, unroll 8 for outstanding loads) ----
    #pragma unroll 8
    for (int it = PRE; it < 32; ++it) {
        const size_t g = base + (size_t)it * 256;
        float4 v = xin[g];
        float4 o;
        o.x = fmaf(v.x, sc.x, bs.x);
        o.y = fmaf(v.y, sc.y, bs.y);
        o.z = fmaf(v.z, sc.z, bs.z);
        o.w = fmaf(v.w, sc.w, bs.w);
        op[g] = o;
    }
}

// ---------------------------------------------------------------------------
extern "C" void kernel_launch(void* const* d_in, const int* in_sizes, int n_in,
                              void* d_out, int out_size, void* d_ws, size_t ws_size,
                              hipStream_t stream) {
    const float* x            = (const float*)d_in[0];
    const float* alpha_u      = (const float*)d_in[1];
    const float* select_noise = (const float*)d_in[2];
    const int*   dom          = (const int*)d_in[3];
    const int*   cls          = (const int*)d_in[4];
    float* out = (float*)d_out;

    // Workspace layout (floats): sumP[B_*S_*C_], sqP[B_*S_*C_]
    float* sumP = (float*)d_ws;
    float* sqP  = sumP + (size_t)B_ * S_ * C_;          // +65536

    // 1) partial stats: 1024 blocks x 256 threads
    stats_partial_kernel<<<B_ * S_, 256, 0, stream>>>(x, sumP, sqP);

    // 2) fused finalize + apply: 2048 blocks x 256 threads
    apply_fused_kernel<<<2048, 256, 0, stream>>>(
        x, sumP, sqP, alpha_u, select_noise, dom, cls, out);
}

// Round 7
// 477.269 us; speedup vs baseline: 1.0342x; 1.0342x over previous
//
#include <hip/hip_runtime.h>
#include <math.h>

// Problem constants (fixed by setup_inputs)
#define B_   64
#define N_   16384
#define C_   64
#define S_   16                    // N-splits for partial stats
#define ROWS_PER_BLK (N_ / S_)     // 1024 rows of C_ floats per stats block
#define EPS_ 1e-6f
#define ALPHA_MAX_ 0.5f

// clang native vector type — required by __builtin_nontemporal_{load,store}
// (HIP's float4 is a class and is rejected). Same 16B layout; supports
// .x/.y/.z/.w swizzles and elementwise arithmetic.
typedef float fvec4 __attribute__((ext_vector_type(4)));

// ---------------------------------------------------------------------------
// Kernel 1: per-(b, channel) partial sum / sumsq over an N-slice.
// Grid: B_*S_ blocks of 256 threads. Each wave reads a contiguous 1 KB
// (float4 per lane), so loads are perfectly coalesced. (Proven; ~5.9 TB/s,
// near the read ceiling. Unchanged — A/B discipline.)
// ---------------------------------------------------------------------------
__global__ __launch_bounds__(256) void stats_partial_kernel(
    const float* __restrict__ x,
    float* __restrict__ sumP,   // [B_*S_][C_]
    float* __restrict__ sqP)    // [B_*S_][C_]
{
    const int bid = blockIdx.x;        // = b*S_ + s
    const int b   = bid >> 4;          // /S_ (S_==16)
    const int s   = bid & 15;

    const float4* xp = (const float4*)(x + ((size_t)b * N_ + (size_t)s * ROWS_PER_BLK) * C_);

    const int tid  = threadIdx.x;
    const int cg   = tid & 15;         // channel-group: covers channels cg*4..cg*4+3
    const int row0 = tid >> 4;         // 0..15

    float4 sum = make_float4(0.f, 0.f, 0.f, 0.f);
    float4 sq  = make_float4(0.f, 0.f, 0.f, 0.f);

    // Each row has C_/4 = 16 float4s; thread walks rows with stride 16.
    #pragma unroll 8
    for (int r = row0; r < ROWS_PER_BLK; r += 16) {
        float4 v = xp[r * 16 + cg];
        sum.x += v.x; sum.y += v.y; sum.z += v.z; sum.w += v.w;
        sq.x = fmaf(v.x, v.x, sq.x); sq.y = fmaf(v.y, v.y, sq.y);
        sq.z = fmaf(v.z, v.z, sq.z); sq.w = fmaf(v.w, v.w, sq.w);
    }

    __shared__ float lds[256][8];
    lds[tid][0] = sum.x; lds[tid][1] = sum.y; lds[tid][2] = sum.z; lds[tid][3] = sum.w;
    lds[tid][4] = sq.x;  lds[tid][5] = sq.y;  lds[tid][6] = sq.z;  lds[tid][7] = sq.w;
    __syncthreads();

    // Reduce across the 16 row-threads sharing each channel-group.
    // tid layout = row0*16 + cg, so strides of 16 preserve cg.
    for (int off = 128; off >= 16; off >>= 1) {
        if (tid < off) {
            #pragma unroll
            for (int k = 0; k < 8; ++k) lds[tid][k] += lds[tid + off][k];
        }
        __syncthreads();
    }

    if (tid < 16) {
        float* sp = sumP + (size_t)bid * C_ + tid * 4;
        float* qp = sqP  + (size_t)bid * C_ + tid * 4;
        sp[0] = lds[tid][0]; sp[1] = lds[tid][1]; sp[2] = lds[tid][2]; sp[3] = lds[tid][3];
        qp[0] = lds[tid][4]; qp[1] = lds[tid][5]; qp[2] = lds[tid][6]; qp[3] = lds[tid][7];
    }
}

// ---------------------------------------------------------------------------
// Kernel 2 (fused finalize + apply): each block owns a contiguous 128 KB
// chunk of one sample (forward order). Threads 0..63 recompute that sample's
// scale/bias from the partials (16 KiB, L2-resident; hidden under the x
// prefetch issued first).
//
// Both streams are NON-TEMPORAL this round:
//  - nt stores: proven +9.4 µs vs plain stores (R6 A/B).
//  - nt loads (NEW): x has zero reuse after this read (harness fills sweep
//    all caches between iterations), so cache allocation on the read stream
//    is pure overhead. Symmetric mechanism to the store win.
// ---------------------------------------------------------------------------
#define PRE 8                      // float4 prefetched per thread before scb
__global__ __launch_bounds__(256) void apply_fused_kernel(
    const float* __restrict__ x,
    const float* __restrict__ sumP,
    const float* __restrict__ sqP,
    const float* __restrict__ alpha_u,      // [B_]
    const float* __restrict__ select_noise, // [B_][B_]
    const int*   __restrict__ dom,          // [B_]
    const int*   __restrict__ cls,          // [B_]
    float* __restrict__ out)
{
    const int tid = threadIdx.x;
    const int b   = blockIdx.x >> 5;          // 32 blocks per sample

    const size_t base = (size_t)blockIdx.x * 8192 + tid;  // float4 index
    const fvec4* __restrict__ xin = (const fvec4*)x;
    fvec4* __restrict__ op = (fvec4*)out;

    // ---- issue nt prefetch of the first PRE float4s (saturate HBM from t0) ----
    fvec4 pre[PRE];
    #pragma unroll
    for (int it = 0; it < PRE; ++it)
        pre[it] = __builtin_nontemporal_load(xin + base + (size_t)it * 256);

    // ---- per-block scale/bias (threads 0..63, c = tid) ----
    __shared__ float scb[2][C_];
    if (tid < C_) {
        const int myCls = cls[b];
        const int myDom = dom[b];
        float best = -1.0f;   // noise is uniform[0,1), any valid score beats -1
        int   bi   = -1;
        for (int j = 0; j < B_; ++j) {
            if (cls[j] == myCls && dom[j] != myDom) {
                float sc = select_noise[b * B_ + j];
                if (sc > best) { best = sc; bi = j; }
            }
        }
        const int idx = (bi < 0) ? b : bi;

        double s1 = 0.0, q1 = 0.0, s2 = 0.0, q2 = 0.0;
        for (int s = 0; s < S_; ++s) {
            s1 += (double)sumP[((size_t)b   * S_ + s) * C_ + tid];
            q1 += (double)sqP [((size_t)b   * S_ + s) * C_ + tid];
            s2 += (double)sumP[((size_t)idx * S_ + s) * C_ + tid];
            q2 += (double)sqP [((size_t)idx * S_ + s) * C_ + tid];
        }
        const double n = (double)N_;
        const float mu   = (float)(s1 / n);
        const float sig  = sqrtf((float)((q1 - s1 * s1 / n) / (n - 1.0)) + EPS_);
        const float mu2  = (float)(s2 / n);
        const float sig2 = sqrtf((float)((q2 - s2 * s2 / n) / (n - 1.0)) + EPS_);

        const float a = alpha_u[b] * ALPHA_MAX_;
        const float mu_mix  = mu  * a + mu2  * (1.0f - a);
        const float sig_mix = sig * a + sig2 * (1.0f - a);

        const float scale = sig_mix / sig;
        scb[0][tid] = scale;
        scb[1][tid] = mu_mix - mu * scale;
    }
    __syncthreads();

    const int c0 = (tid & 15) * 4;
    fvec4 sc, bs;
    sc.x = scb[0][c0]; sc.y = scb[0][c0+1]; sc.z = scb[0][c0+2]; sc.w = scb[0][c0+3];
    bs.x = scb[1][c0]; bs.y = scb[1][c0+1]; bs.z = scb[1][c0+2]; bs.w = scb[1][c0+3];

    // ---- drain prefetched portion ----
    #pragma unroll
    for (int it = 0; it < PRE; ++it) {
        fvec4 o = pre[it] * sc + bs;
        __builtin_nontemporal_store(o, op + base + (size_t)it * 256);
    }
    // ---- stream the rest (24 iterations, unroll 8 for outstanding loads) ----
    #pragma unroll 8
    for (int it = PRE; it < 32; ++it) {
        const size_t g = base + (size_t)it * 256;
        fvec4 v = __builtin_nontemporal_load(xin + g);
        fvec4 o = v * sc + bs;
        __builtin_nontemporal_store(o, op + g);
    }
}

// ---------------------------------------------------------------------------
extern "C" void kernel_launch(void* const* d_in, const int* in_sizes, int n_in,
                              void* d_out, int out_size, void* d_ws, size_t ws_size,
                              hipStream_t stream) {
    const float* x            = (const float*)d_in[0];
    const float* alpha_u      = (const float*)d_in[1];
    const float* select_noise = (const float*)d_in[2];
    const int*   dom          = (const int*)d_in[3];
    const int*   cls          = (const int*)d_in[4];
    float* out = (float*)d_out;

    // Workspace layout (floats): sumP[B_*S_*C_], sqP[B_*S_*C_]
    float* sumP = (float*)d_ws;
    float* sqP  = sumP + (size_t)B_ * S_ * C_;          // +65536

    // 1) partial stats: 1024 blocks x 256 threads
    stats_partial_kernel<<<B_ * S_, 256, 0, stream>>>(x, sumP, sqP);

    // 2) fused finalize + apply: 2048 blocks x 256 threads (nt loads + nt stores)
    apply_fused_kernel<<<2048, 256, 0, stream>>>(
        x, sumP, sqP, alpha_u, select_noise, dom, cls, out);
}

// Round 8
// 472.764 us; speedup vs baseline: 1.0441x; 1.0095x over previous
//
#include <hip/hip_runtime.h>
#include <math.h>

// Problem constants (fixed by setup_inputs)
#define B_   64
#define N_   16384
#define C_   64
#define S_   16                    // N-splits for partial stats
#define ROWS_PER_BLK (N_ / S_)     // 1024 rows of C_ floats per stats block
#define EPS_ 1e-6f
#define ALPHA_MAX_ 0.5f

// clang native vector type — required by __builtin_nontemporal_{load,store}
// (HIP's float4 is a class and is rejected). Same 16B layout; supports
// .x/.y/.z/.w swizzles and elementwise arithmetic.
typedef float fvec4 __attribute__((ext_vector_type(4)));

// ---------------------------------------------------------------------------
// Kernel 1: per-(b, channel) partial sum / sumsq over an N-slice.
// Grid: B_*S_ blocks of 256 threads. Each wave reads a contiguous 1 KB
// (float4 per lane), so loads are perfectly coalesced.
//
// NT loads this round: the L3 hand-off theory is dead (harness fills sweep
// all caches between my dispatches), so stats' cache allocations serve
// nobody. Same mechanism as the two proven nt wins in apply
// (stores +9.4 µs, loads +6.9 µs).
// ---------------------------------------------------------------------------
__global__ __launch_bounds__(256) void stats_partial_kernel(
    const float* __restrict__ x,
    float* __restrict__ sumP,   // [B_*S_][C_]
    float* __restrict__ sqP)    // [B_*S_][C_]
{
    const int bid = blockIdx.x;        // = b*S_ + s
    const int b   = bid >> 4;          // /S_ (S_==16)
    const int s   = bid & 15;

    const fvec4* xp = (const fvec4*)(x + ((size_t)b * N_ + (size_t)s * ROWS_PER_BLK) * C_);

    const int tid  = threadIdx.x;
    const int cg   = tid & 15;         // channel-group: covers channels cg*4..cg*4+3
    const int row0 = tid >> 4;         // 0..15

    fvec4 sum = (fvec4)(0.f);
    fvec4 sq  = (fvec4)(0.f);

    // Each row has C_/4 = 16 float4s; thread walks rows with stride 16.
    #pragma unroll 8
    for (int r = row0; r < ROWS_PER_BLK; r += 16) {
        fvec4 v = __builtin_nontemporal_load(xp + r * 16 + cg);
        sum += v;
        sq  += v * v;
    }

    __shared__ float lds[256][8];
    lds[tid][0] = sum.x; lds[tid][1] = sum.y; lds[tid][2] = sum.z; lds[tid][3] = sum.w;
    lds[tid][4] = sq.x;  lds[tid][5] = sq.y;  lds[tid][6] = sq.z;  lds[tid][7] = sq.w;
    __syncthreads();

    // Reduce across the 16 row-threads sharing each channel-group.
    // tid layout = row0*16 + cg, so strides of 16 preserve cg.
    for (int off = 128; off >= 16; off >>= 1) {
        if (tid < off) {
            #pragma unroll
            for (int k = 0; k < 8; ++k) lds[tid][k] += lds[tid + off][k];
        }
        __syncthreads();
    }

    if (tid < 16) {
        float* sp = sumP + (size_t)bid * C_ + tid * 4;
        float* qp = sqP  + (size_t)bid * C_ + tid * 4;
        sp[0] = lds[tid][0]; sp[1] = lds[tid][1]; sp[2] = lds[tid][2]; sp[3] = lds[tid][3];
        qp[0] = lds[tid][4]; qp[1] = lds[tid][5]; qp[2] = lds[tid][6]; qp[3] = lds[tid][7];
    }
}

// ---------------------------------------------------------------------------
// Kernel 2 (fused finalize + apply): each block owns a contiguous 128 KB
// chunk of one sample (forward order). Threads 0..63 recompute that sample's
// scale/bias from the partials (16 KiB, L2-resident; hidden under the x
// prefetch issued first).
//
// Both streams NON-TEMPORAL (both A/B-proven: stores +9.4 µs, loads +6.9 µs).
// UNCHANGED from R7 — A/B discipline.
// ---------------------------------------------------------------------------
#define PRE 8                      // float4 prefetched per thread before scb
__global__ __launch_bounds__(256) void apply_fused_kernel(
    const float* __restrict__ x,
    const float* __restrict__ sumP,
    const float* __restrict__ sqP,
    const float* __restrict__ alpha_u,      // [B_]
    const float* __restrict__ select_noise, // [B_][B_]
    const int*   __restrict__ dom,          // [B_]
    const int*   __restrict__ cls,          // [B_]
    float* __restrict__ out)
{
    const int tid = threadIdx.x;
    const int b   = blockIdx.x >> 5;          // 32 blocks per sample

    const size_t base = (size_t)blockIdx.x * 8192 + tid;  // float4 index
    const fvec4* __restrict__ xin = (const fvec4*)x;
    fvec4* __restrict__ op = (fvec4*)out;

    // ---- issue nt prefetch of the first PRE float4s (saturate HBM from t0) ----
    fvec4 pre[PRE];
    #pragma unroll
    for (int it = 0; it < PRE; ++it)
        pre[it] = __builtin_nontemporal_load(xin + base + (size_t)it * 256);

    // ---- per-block scale/bias (threads 0..63, c = tid) ----
    __shared__ float scb[2][C_];
    if (tid < C_) {
        const int myCls = cls[b];
        const int myDom = dom[b];
        float best = -1.0f;   // noise is uniform[0,1), any valid score beats -1
        int   bi   = -1;
        for (int j = 0; j < B_; ++j) {
            if (cls[j] == myCls && dom[j] != myDom) {
                float sc = select_noise[b * B_ + j];
                if (sc > best) { best = sc; bi = j; }
            }
        }
        const int idx = (bi < 0) ? b : bi;

        double s1 = 0.0, q1 = 0.0, s2 = 0.0, q2 = 0.0;
        for (int s = 0; s < S_; ++s) {
            s1 += (double)sumP[((size_t)b   * S_ + s) * C_ + tid];
            q1 += (double)sqP [((size_t)b   * S_ + s) * C_ + tid];
            s2 += (double)sumP[((size_t)idx * S_ + s) * C_ + tid];
            q2 += (double)sqP [((size_t)idx * S_ + s) * C_ + tid];
        }
        const double n = (double)N_;
        const float mu   = (float)(s1 / n);
        const float sig  = sqrtf((float)((q1 - s1 * s1 / n) / (n - 1.0)) + EPS_);
        const float mu2  = (float)(s2 / n);
        const float sig2 = sqrtf((float)((q2 - s2 * s2 / n) / (n - 1.0)) + EPS_);

        const float a = alpha_u[b] * ALPHA_MAX_;
        const float mu_mix  = mu  * a + mu2  * (1.0f - a);
        const float sig_mix = sig * a + sig2 * (1.0f - a);

        const float scale = sig_mix / sig;
        scb[0][tid] = scale;
        scb[1][tid] = mu_mix - mu * scale;
    }
    __syncthreads();

    const int c0 = (tid & 15) * 4;
    fvec4 sc, bs;
    sc.x = scb[0][c0]; sc.y = scb[0][c0+1]; sc.z = scb[0][c0+2]; sc.w = scb[0][c0+3];
    bs.x = scb[1][c0]; bs.y = scb[1][c0+1]; bs.z = scb[1][c0+2]; bs.w = scb[1][c0+3];

    // ---- drain prefetched portion ----
    #pragma unroll
    for (int it = 0; it < PRE; ++it) {
        fvec4 o = pre[it] * sc + bs;
        __builtin_nontemporal_store(o, op + base + (size_t)it * 256);
    }
    // ---- stream the rest (24 iterations, unroll 8 for outstanding loads) ----
    #pragma unroll 8
    for (int it = PRE; it < 32; ++it) {
        const size_t g = base + (size_t)it * 256;
        fvec4 v = __builtin_nontemporal_load(xin + g);
        fvec4 o = v * sc + bs;
        __builtin_nontemporal_store(o, op + g);
    }
}

// ---------------------------------------------------------------------------
extern "C" void kernel_launch(void* const* d_in, const int* in_sizes, int n_in,
                              void* d_out, int out_size, void* d_ws, size_t ws_size,
                              hipStream_t stream) {
    const float* x            = (const float*)d_in[0];
    const float* alpha_u      = (const float*)d_in[1];
    const float* select_noise = (const float*)d_in[2];
    const int*   dom          = (const int*)d_in[3];
    const int*   cls          = (const int*)d_in[4];
    float* out = (float*)d_out;

    // Workspace layout (floats): sumP[B_*S_*C_], sqP[B_*S_*C_]
    float* sumP = (float*)d_ws;
    float* sqP  = sumP + (size_t)B_ * S_ * C_;          // +65536

    // 1) partial stats: 1024 blocks x 256 threads (nt loads)
    stats_partial_kernel<<<B_ * S_, 256, 0, stream>>>(x, sumP, sqP);

    // 2) fused finalize + apply: 2048 blocks x 256 threads (nt loads + nt stores)
    apply_fused_kernel<<<2048, 256, 0, stream>>>(
        x, sumP, sqP, alpha_u, select_noise, dom, cls, out);
}